// Round 1
// baseline (265.615 us; speedup 1.0000x reference)
//
#include <hip/hip_runtime.h>
#include <hip/hip_bf16.h>
#include <math.h>

// Problem constants
#define B_ 4
#define L_ 4096
#define E_ 1024
#define H_ 16
#define D_ 64
#define N_ 64          // B*H heads
#define D2_ 128        // feature dim 2*D
#define EPS_ 1e-6f

#define CH_ 8              // phase1 L-chunks (512 blocks, 2/CU; halves partial traffic)
#define LC_ (L_ / CH_)     // 512 rows per phase1 block
#define LT_ 64             // rows per LDS stage
#define NST_ (LC_ / LT_)   // 8 stages

#define DANG_ 3.83495197e-4f  // 0.5*pi/L

typedef short short8 __attribute__((ext_vector_type(8)));
typedef float f32x4 __attribute__((ext_vector_type(4)));
typedef unsigned int u32;
typedef unsigned short u16;

static __device__ __forceinline__ u32 pack2bf(float a, float b) {
  union { __hip_bfloat16 h; u16 s; } x, y;
  x.h = __float2bfloat16(a);
  y.h = __float2bfloat16(b);
  return (u32)x.s | ((u32)y.s << 16);
}

static __device__ __forceinline__ short bf1(float a) {
  union { __hip_bfloat16 h; short s; } x;
  x.h = __float2bfloat16(a);
  return x.s;
}

// ---------------------------------------------------------------------------
// Phase 1 (MFMA): partial kv[d][m] = sum_l k_[l][d] * v[l][m], ksum[d]=sum k_
// Software-pipelined: stage st+1's global loads issue before stage st's
// LDS writes, so HBM latency hides under compute+MFMA+barriers.
// Mask via one coalesced load/wave + __shfl; trig per-thread __sincosf
// (removes the old msh/ssh/csh arrays and one barrier per stage).
// ---------------------------------------------------------------------------
__global__ __launch_bounds__(256, 2) void phase1_mfma(
    const float* __restrict__ k, const float* __restrict__ v,
    const float* __restrict__ mask,
    float* __restrict__ part_kv, float* __restrict__ part_ks) {
  __shared__ __align__(16) u16 ka[D2_ * 72];
  __shared__ __align__(16) u16 vt[D_ * 72];

  const int bid = blockIdx.x;
  const int n = bid & 63;
  const int ch = bid >> 6;
  const int b = n >> 4;
  const int h = n & 15;
  const int t = threadIdx.x;
  const int wv = t >> 6;
  const int lane = t & 63;
  const int c_lo = lane & 15;
  const int lp = lane >> 4;       // quad
  const int c = wv * 16 + c_lo;   // staging column 0..63

  f32x4 acc[2][4];
#pragma unroll
  for (int i = 0; i < 2; ++i)
#pragma unroll
    for (int j = 0; j < 4; ++j) acc[i][j] = (f32x4)0.f;
  float kss = 0.f, ksc = 0.f;

  const int l0 = ch * LC_;
  const size_t gb0 = (size_t)(b * L_ + l0) * E_ + h * 64 + c;

  // double-buffered prefetch registers (static indexing only)
  float Ak0[8], Ak1[8], Av0[8], Av1[8], Am;
  float Bk0[8], Bk1[8], Bv0[8], Bv1[8], Bm;

#define P1_PREF(Rk0, Rk1, Rv0, Rv1, Rm, S)                                   \
  do {                                                                       \
    const size_t gs_ = gb0 + (size_t)(S) * (LT_ * E_);                       \
    _Pragma("unroll") for (int i_ = 0; i_ < 8; ++i_) {                       \
      const size_t g0_ = gs_ + (size_t)(8 * i_ + 2 * lp) * E_;               \
      Rk0[i_] = k[g0_];                                                      \
      Rk1[i_] = k[g0_ + E_];                                                 \
      Rv0[i_] = v[g0_];                                                      \
      Rv1[i_] = v[g0_ + E_];                                                 \
    }                                                                        \
    Rm = mask[(size_t)b * L_ + l0 + (S) * LT_ + lane];                       \
  } while (0)

#define P1_STAGE(Rk0, Rk1, Rv0, Rv1, Rm, S)                                  \
  do {                                                                       \
    const int lb_ = l0 + (S) * LT_;                                          \
    _Pragma("unroll") for (int i_ = 0; i_ < 8; ++i_) {                       \
      const int l_ = 8 * i_ + 2 * lp;                                        \
      const float m0_ = __shfl(Rm, l_);                                      \
      const float m1_ = __shfl(Rm, l_ + 1);                                  \
      float s0_, c0_, s1_, c1_;                                              \
      __sincosf((float)(lb_ + l_ + 1) * DANG_, &s0_, &c0_);                  \
      __sincosf((float)(lb_ + l_ + 2) * DANG_, &s1_, &c1_);                  \
      const float kr0_ = fmaxf(Rk0[i_], 0.f) * m0_;                          \
      const float kr1_ = fmaxf(Rk1[i_], 0.f) * m1_;                          \
      const float ks0_ = kr0_ * s0_, ks1_ = kr1_ * s1_;                      \
      const float kc0_ = kr0_ * c0_, kc1_ = kr1_ * c1_;                      \
      const int li_ = 4 * i_ + lp;                                           \
      ((u32*)ka)[c * 36 + li_] = pack2bf(ks0_, ks1_);                        \
      ((u32*)ka)[(c + 64) * 36 + li_] = pack2bf(kc0_, kc1_);                 \
      ((u32*)vt)[c * 36 + li_] = pack2bf(Rv0[i_] * m0_, Rv1[i_] * m1_);      \
      kss += ks0_ + ks1_;                                                    \
      ksc += kc0_ + kc1_;                                                    \
    }                                                                        \
  } while (0)

#define P1_MMA()                                                             \
  do {                                                                       \
    _Pragma("unroll") for (int kk_ = 0; kk_ < 2; ++kk_) {                    \
      const int colo_ = kk_ * 32 + lp * 8;                                   \
      short8 af_[2], bf_[4];                                                 \
      _Pragma("unroll") for (int dt_ = 0; dt_ < 2; ++dt_)                    \
          af_[dt_] =                                                         \
              *(const short8*)&ka[(wv * 32 + dt_ * 16 + c_lo) * 72 + colo_]; \
      _Pragma("unroll") for (int mt_ = 0; mt_ < 4; ++mt_)                    \
          bf_[mt_] = *(const short8*)&vt[(mt_ * 16 + c_lo) * 72 + colo_];    \
      _Pragma("unroll") for (int dt_ = 0; dt_ < 2; ++dt_)                    \
          _Pragma("unroll") for (int mt_ = 0; mt_ < 4; ++mt_)                \
              acc[dt_][mt_] = __builtin_amdgcn_mfma_f32_16x16x32_bf16(       \
                  af_[dt_], bf_[mt_], acc[dt_][mt_], 0, 0, 0);               \
    }                                                                        \
  } while (0)

  P1_PREF(Ak0, Ak1, Av0, Av1, Am, 0);
  for (int st = 0; st < NST_; st += 2) {
    __syncthreads();  // previous MFMA readers done -> LDS writable
    P1_PREF(Bk0, Bk1, Bv0, Bv1, Bm, st + 1);  // issue next-stage loads early
    P1_STAGE(Ak0, Ak1, Av0, Av1, Am, st);
    __syncthreads();
    P1_MMA();
    __syncthreads();
    if (st + 2 < NST_) P1_PREF(Ak0, Ak1, Av0, Av1, Am, st + 2);
    P1_STAGE(Bk0, Bk1, Bv0, Bv1, Bm, st + 1);
    __syncthreads();
    P1_MMA();
  }

  // write partial kv (fp32). C layout: row(d)=quad*4+r, col(m)=lane&15
  const size_t pbase = (size_t)(ch * N_ + n) * (D2_ * D_);
#pragma unroll
  for (int dt = 0; dt < 2; ++dt) {
    const int d = wv * 32 + dt * 16 + lp * 4;
#pragma unroll
    for (int mt = 0; mt < 4; ++mt) {
      const int mcol = mt * 16 + c_lo;
#pragma unroll
      for (int r = 0; r < 4; ++r)
        part_kv[pbase + (size_t)(d + r) * D_ + mcol] = acc[dt][mt][r];
    }
  }
  // ksum partials: reduce over lp groups (lanes +-16, +-32)
  kss += __shfl_xor(kss, 16); kss += __shfl_xor(kss, 32);
  ksc += __shfl_xor(ksc, 16); ksc += __shfl_xor(ksc, 32);
  if (lp == 0) {
    part_ks[(size_t)(ch * N_ + n) * D2_ + c] = kss;
    part_ks[(size_t)(ch * N_ + n) * D2_ + c + 64] = ksc;
  }
}

// ---------------------------------------------------------------------------
// Reduce: sum chunk partials; emit kvT[n][m][d] bf16 + ksum fp32.
// 512 blocks (8 e-slices per head), float4 loads, small LDS transpose.
// ---------------------------------------------------------------------------
__global__ __launch_bounds__(256) void reduce_t(
    const float* __restrict__ part_kv, const float* __restrict__ part_ks,
    u16* __restrict__ kvt, float* __restrict__ ks) {
  __shared__ __align__(16) float tsh[16 * 68];
  const int bid = blockIdx.x;
  const int n = bid >> 3;
  const int sl = bid & 7;
  const int t = threadIdx.x;

  const int e0 = sl * 1024 + t * 4;  // covers d=sl*16..+16, m=0..63
  f32x4 s = (f32x4)0.f;
#pragma unroll
  for (int cc = 0; cc < CH_; ++cc)
    s += *(const f32x4*)&part_kv[(size_t)(cc * N_ + n) * (D2_ * D_) + e0];
  *(f32x4*)&tsh[(t >> 4) * 68 + (t & 15) * 4] = s;

  if (sl == 0 && t < D2_) {
    float ss = 0.f;
#pragma unroll
    for (int cc = 0; cc < CH_; ++cc)
      ss += part_ks[(size_t)(cc * N_ + n) * D2_ + t];
    ks[n * D2_ + t] = ss;
  }
  __syncthreads();

  // transpose out: thread -> m = t>>2, 4 consecutive d
  const int m = t >> 2;
  const int d4 = (t & 3) * 4;
  const u32 lo = pack2bf(tsh[(d4 + 0) * 68 + m], tsh[(d4 + 1) * 68 + m]);
  const u32 hi = pack2bf(tsh[(d4 + 2) * 68 + m], tsh[(d4 + 3) * 68 + m]);
  uint2 pk; pk.x = lo; pk.y = hi;
  *(uint2*)&kvt[(size_t)n * (D2_ * D_) + (size_t)m * D2_ + sl * 16 + d4] = pk;
}

// ---------------------------------------------------------------------------
// Phase 2 (MFMA), LDS-free: K-dim is d, contiguous in both q and kvt[m][d],
// so A and B fragments load straight from global. No barriers, no LDS.
// A-lane: q row = l0 + wv*16 + c_lo, cols quad*8-based (x2 for s/c halves).
// B-lane: kvt[(mt*16+c_lo)][kk*32+quad*8..+7] (16B aligned, L2-resident).
// z via 5th accumulator whose B col 0 is ksum.
// ---------------------------------------------------------------------------
__global__ __launch_bounds__(256, 4) void phase2_mfma(
    const float* __restrict__ q, const u16* __restrict__ kvt,
    const float* __restrict__ ks, float* __restrict__ out) {
  const int bid = blockIdx.x;
  const int n = bid & 63;
  const int lc = bid >> 6;
  const int b = n >> 4, h = n & 15;
  const int t = threadIdx.x;
  const int wv = t >> 6, lane = t & 63;
  const int c_lo = lane & 15, quad = lane >> 4;
  const int l0 = lc * 64;
  const int row = l0 + wv * 16 + c_lo;  // A-operand row this lane feeds

  const float* qr = q + (size_t)(b * L_ + row) * E_ + h * 64;
  const f32x4 q0 = *(const f32x4*)(qr + quad * 8);
  const f32x4 q1 = *(const f32x4*)(qr + quad * 8 + 4);
  const f32x4 q2 = *(const f32x4*)(qr + 32 + quad * 8);
  const f32x4 q3 = *(const f32x4*)(qr + 32 + quad * 8 + 4);

  float sv, cv;
  __sincosf((float)(row + 1) * DANG_, &sv, &cv);

  // A fragments: af[kk] = q_[row][kk*32 + quad*8 .. +7]
  short8 af[4];
#pragma unroll
  for (int j = 0; j < 4; ++j) {
    const float a = fmaxf(q0[j], 0.f);
    const float e = fmaxf(q1[j], 0.f);
    const float f = fmaxf(q2[j], 0.f);
    const float g = fmaxf(q3[j], 0.f);
    af[0][j] = bf1(a * sv); af[0][j + 4] = bf1(e * sv);
    af[1][j] = bf1(f * sv); af[1][j + 4] = bf1(g * sv);
    af[2][j] = bf1(a * cv); af[2][j + 4] = bf1(e * cv);
    af[3][j] = bf1(f * cv); af[3][j + 4] = bf1(g * cv);
  }

  // ksum B-fragments: col 0 = ksum, other cols 0
  const float* ksn = ks + n * D2_;
  short8 bks[4];
#pragma unroll
  for (int kk = 0; kk < 4; ++kk) {
    const f32x4 ka_ = *(const f32x4*)(ksn + kk * 32 + quad * 8);
    const f32x4 kb_ = *(const f32x4*)(ksn + kk * 32 + quad * 8 + 4);
    short8 tt = {0, 0, 0, 0, 0, 0, 0, 0};
    if (c_lo == 0) {
#pragma unroll
      for (int j = 0; j < 4; ++j) {
        tt[j] = bf1(ka_[j]);
        tt[j + 4] = bf1(kb_[j]);
      }
    }
    bks[kk] = tt;
  }

  const u16* kvh = kvt + (size_t)n * (D2_ * D_);
  f32x4 acc[4];
#pragma unroll
  for (int mt = 0; mt < 4; ++mt) acc[mt] = (f32x4)0.f;
  f32x4 acc5 = (f32x4)0.f;

#pragma unroll
  for (int kk = 0; kk < 4; ++kk) {
#pragma unroll
    for (int mt = 0; mt < 4; ++mt) {
      const short8 bfr =
          *(const short8*)&kvh[(mt * 16 + c_lo) * D2_ + kk * 32 + quad * 8];
      acc[mt] = __builtin_amdgcn_mfma_f32_16x16x32_bf16(af[kk], bfr, acc[mt], 0, 0, 0);
    }
    acc5 = __builtin_amdgcn_mfma_f32_16x16x32_bf16(af[kk], bks[kk], acc5, 0, 0, 0);
  }

  // epilogue: z from acc5 col 0 (lane quad*16), scale, store
#pragma unroll
  for (int r = 0; r < 4; ++r) {
    const float den = __shfl(acc5[r], quad * 16);
    const float z = 1.f / fmaxf(den, EPS_);
    const int gl = l0 + wv * 16 + quad * 4 + r;
    const size_t ob = (size_t)n * (L_ * D_) + (size_t)gl * D_;
#pragma unroll
    for (int mt = 0; mt < 4; ++mt)
      out[ob + mt * 16 + c_lo] = acc[mt][r] * z;
  }
}

// ---------------------------------------------------------------------------
extern "C" void kernel_launch(void* const* d_in, const int* in_sizes, int n_in,
                              void* d_out, int out_size, void* d_ws,
                              size_t ws_size, hipStream_t stream) {
  const float* q = (const float*)d_in[0];
  const float* k = (const float*)d_in[1];
  const float* v = (const float*)d_in[2];
  const float* mask = (const float*)d_in[3];
  float* out = (float*)d_out;

  float* part_kv = (float*)d_ws;                             // 8*64*8192 f32 = 16 MB
  float* part_ks = part_kv + (size_t)CH_ * N_ * D2_ * D_;    // 8*64*128 f32
  u16* kvt = (u16*)(part_ks + (size_t)CH_ * N_ * D2_);       // 64*8192 bf16 = 1 MB
  float* ks = (float*)(kvt + (size_t)N_ * D2_ * D_);         // 64*128 f32

  phase1_mfma<<<dim3(CH_ * N_), dim3(256), 0, stream>>>(k, v, mask, part_kv, part_ks);
  reduce_t<<<dim3(N_ * 8), dim3(256), 0, stream>>>(part_kv, part_ks, kvt, ks);
  phase2_mfma<<<dim3(N_ * 64), dim3(256), 0, stream>>>(q, kvt, ks, out);
}